// Round 1
// baseline (1623.068 us; speedup 1.0000x reference)
//
#include <hip/hip_runtime.h>

#define N_NODES 100000
#define N_EDGES 3200000
#define N_GRAPHS 2048
#define MOL 78
#define HID 32
#define OUTD 128
#define BN_EPS 1e-5f

#define NSCAN (N_NODES + 1)
#define SCAN_CHUNK 1024
#define NBLK ((NSCAN + SCAN_CHUNK - 1) / SCAN_CHUNK)  // 98

// ---------------- CSR build ----------------

__global__ void hist_kernel(const int* __restrict__ dst, int* __restrict__ deg) {
    int e = blockIdx.x * blockDim.x + threadIdx.x;
    if (e < N_EDGES) atomicAdd(&deg[dst[e]], 1);
}

__global__ void scan_partial_kernel(const int* __restrict__ deg, int* __restrict__ bsum) {
    int b = blockIdx.x, t = threadIdx.x;
    int base = b * SCAN_CHUNK + t * 4;
    int s = 0;
#pragma unroll
    for (int k = 0; k < 4; k++) {
        int i = base + k;
        if (i < NSCAN) s += deg[i];
    }
    __shared__ int red[256];
    red[t] = s;
    __syncthreads();
    for (int off = 128; off; off >>= 1) {
        if (t < off) red[t] += red[t + off];
        __syncthreads();
    }
    if (t == 0) bsum[b] = red[0];
}

__global__ void scan_block_kernel(const int* __restrict__ bsum, int* __restrict__ boff) {
    if (threadIdx.x == 0 && blockIdx.x == 0) {
        int r = 0;
        for (int b = 0; b < NBLK; b++) {
            boff[b] = r;
            r += bsum[b];
        }
    }
}

__global__ void scan_final_kernel(const int* __restrict__ deg, const int* __restrict__ boff,
                                  int* __restrict__ row_start) {
    int b = blockIdx.x, t = threadIdx.x;
    int base = b * SCAN_CHUNK + t * 4;
    int v[4];
    int tot = 0;
#pragma unroll
    for (int k = 0; k < 4; k++) {
        int i = base + k;
        v[k] = (i < NSCAN) ? deg[i] : 0;
        tot += v[k];
    }
    __shared__ int sc[256];
    sc[t] = tot;
    __syncthreads();
    // Hillis-Steele inclusive scan over 256 thread totals
    for (int off = 1; off < 256; off <<= 1) {
        int add = (t >= off) ? sc[t - off] : 0;
        __syncthreads();
        sc[t] += add;
        __syncthreads();
    }
    int run = boff[b] + sc[t] - tot;  // exclusive prefix for this thread
#pragma unroll
    for (int k = 0; k < 4; k++) {
        int i = base + k;
        if (i < NSCAN) row_start[i] = run;
        run += v[k];
    }
}

__global__ void cursor_copy_kernel(const int* __restrict__ row_start, int* __restrict__ cursor) {
    int i = blockIdx.x * blockDim.x + threadIdx.x;
    if (i < N_NODES) cursor[i] = row_start[i];
}

__global__ void scatter_kernel(const int* __restrict__ src, const int* __restrict__ dst,
                               int* __restrict__ cursor, int* __restrict__ csr) {
    int e = blockIdx.x * blockDim.x + threadIdx.x;
    if (e < N_EDGES) {
        int d = dst[e];
        int p = atomicAdd(&cursor[d], 1);
        csr[p] = src[e];
    }
}

// ---------------- Aggregation ----------------

// Layer 0: 78-dim input, no affine. One wave (64 lanes) per node.
__global__ void agg78_kernel(const float* __restrict__ x, const int* __restrict__ rs,
                             const int* __restrict__ csr, float* __restrict__ agg) {
    int wave = (blockIdx.x * blockDim.x + threadIdx.x) >> 6;
    int lane = threadIdx.x & 63;
    if (wave >= N_NODES) return;
    const int node = wave;
    float a0 = x[(size_t)node * MOL + lane];
    float a1 = (lane < MOL - 64) ? x[(size_t)node * MOL + 64 + lane] : 0.f;
    int e0 = rs[node], e1 = rs[node + 1];
    for (int k = e0; k < e1; k++) {
        int j = csr[k];
        a0 += x[(size_t)j * MOL + lane];
        if (lane < MOL - 64) a1 += x[(size_t)j * MOL + 64 + lane];
    }
    agg[(size_t)node * MOL + lane] = a0;
    if (lane < MOL - 64) agg[(size_t)node * MOL + 64 + lane] = a1;
}

// Layers 1..4: 32-dim, fused BN affine of previous layer applied to every read.
// One half-wave (32 lanes) per node.
__global__ void agg32_kernel(const float* __restrict__ hin, const int* __restrict__ rs,
                             const int* __restrict__ csr, const float* __restrict__ scsh,
                             float* __restrict__ aggout) {
    int gt = blockIdx.x * blockDim.x + threadIdx.x;
    int node = gt >> 5;
    if (node >= N_NODES) return;
    int c = gt & 31;
    float sc = scsh[c], sh = scsh[HID + c];
    float a = fmaf(hin[(size_t)node * HID + c], sc, sh);
    int e0 = rs[node], e1 = rs[node + 1];
    for (int k = e0; k < e1; k++) {
        int j = csr[k];
        a += fmaf(hin[(size_t)j * HID + c], sc, sh);
    }
    aggout[(size_t)node * HID + c] = a;
}

// ---------------- MLP + BN stats ----------------

template <int KIN>
__global__ __launch_bounds__(256) void mlp_kernel(const float* __restrict__ in,
                                                  const float* __restrict__ W1,
                                                  const float* __restrict__ B1,
                                                  const float* __restrict__ W2,
                                                  const float* __restrict__ B2,
                                                  float* __restrict__ out,
                                                  float* __restrict__ sums) {
    __shared__ float w1s[KIN * HID];
    __shared__ float w2s[HID * HID];
    __shared__ float bs[2 * HID];
    __shared__ float ssum[2 * HID];
    for (int i = threadIdx.x; i < KIN * HID; i += 256) w1s[i] = W1[i];
    for (int i = threadIdx.x; i < HID * HID; i += 256) w2s[i] = W2[i];
    if (threadIdx.x < HID) {
        bs[threadIdx.x] = B1[threadIdx.x];
        bs[HID + threadIdx.x] = B2[threadIdx.x];
    }
    if (threadIdx.x < 2 * HID) ssum[threadIdx.x] = 0.f;
    __syncthreads();

    const int node = blockIdx.x * 256 + threadIdx.x;
    const bool active = node < N_NODES;

    float acc[HID];
#pragma unroll
    for (int j = 0; j < HID; j++) acc[j] = bs[j];

    if (active) {
        const float* row = in + (size_t)node * KIN;
        const float4* w1v = (const float4*)w1s;
        for (int k = 0; k < KIN; k++) {
            float xv = row[k];
#pragma unroll
            for (int q = 0; q < 8; q++) {
                float4 wv = w1v[k * 8 + q];
                acc[4 * q + 0] = fmaf(xv, wv.x, acc[4 * q + 0]);
                acc[4 * q + 1] = fmaf(xv, wv.y, acc[4 * q + 1]);
                acc[4 * q + 2] = fmaf(xv, wv.z, acc[4 * q + 2]);
                acc[4 * q + 3] = fmaf(xv, wv.w, acc[4 * q + 3]);
            }
        }
    }

    float h2[HID];
#pragma unroll
    for (int j = 0; j < HID; j++) h2[j] = bs[HID + j];
    const float4* w2v = (const float4*)w2s;
#pragma unroll
    for (int k = 0; k < HID; k++) {
        float v = fmaxf(acc[k], 0.f);
#pragma unroll
        for (int q = 0; q < 8; q++) {
            float4 wv = w2v[k * 8 + q];
            h2[4 * q + 0] = fmaf(v, wv.x, h2[4 * q + 0]);
            h2[4 * q + 1] = fmaf(v, wv.y, h2[4 * q + 1]);
            h2[4 * q + 2] = fmaf(v, wv.z, h2[4 * q + 2]);
            h2[4 * q + 3] = fmaf(v, wv.w, h2[4 * q + 3]);
        }
    }
#pragma unroll
    for (int j = 0; j < HID; j++) h2[j] = fmaxf(h2[j], 0.f);

    if (active) {
        float4* o = (float4*)(out + (size_t)node * HID);
#pragma unroll
        for (int q = 0; q < 8; q++)
            o[q] = make_float4(h2[4 * q], h2[4 * q + 1], h2[4 * q + 2], h2[4 * q + 3]);
    }

    // BN stats: per-column sum & sumsq, wave shuffle reduce -> LDS -> global
    int lane = threadIdx.x & 63;
#pragma unroll
    for (int j = 0; j < HID; j++) {
        float v = active ? h2[j] : 0.f;
        float v2 = v * v;
#pragma unroll
        for (int off = 32; off; off >>= 1) {
            v += __shfl_down(v, off, 64);
            v2 += __shfl_down(v2, off, 64);
        }
        if (lane == 0) {
            atomicAdd(&ssum[j], v);
            atomicAdd(&ssum[HID + j], v2);
        }
    }
    __syncthreads();
    if (threadIdx.x < 2 * HID) atomicAdd(&sums[threadIdx.x], ssum[threadIdx.x]);
}

__global__ void bnfin_kernel(const float* __restrict__ sums, const float* __restrict__ g,
                             const float* __restrict__ bt, float* __restrict__ scsh) {
    int j = threadIdx.x;
    if (j < HID) {
        float m = sums[j] * (1.0f / N_NODES);
        float var = sums[HID + j] * (1.0f / N_NODES) - m * m;
        var = fmaxf(var, 0.f);
        float sc = g[j] * rsqrtf(var + BN_EPS);
        scsh[j] = sc;
        scsh[HID + j] = bt[j] - m * sc;
    }
}

// ---------------- Pooling + FC ----------------

__global__ void pool_kernel(const float* __restrict__ h, const int* __restrict__ batch,
                            const float* __restrict__ scsh, float* __restrict__ pooled) {
    int gt = blockIdx.x * blockDim.x + threadIdx.x;
    if (gt >= N_NODES * HID) return;
    int node = gt >> 5;
    int c = gt & 31;
    int g = batch[node];
    float v = fmaf(h[gt], scsh[c], scsh[HID + c]);
    atomicAdd(&pooled[g * HID + c], v);
}

__global__ void fc_kernel(const float* __restrict__ pooled, const float* __restrict__ fcw,
                          const float* __restrict__ fcb, float* __restrict__ out) {
    __shared__ float w[HID * OUTD];
    for (int i = threadIdx.x; i < HID * OUTD; i += 256) w[i] = fcw[i];
    __syncthreads();
    int idx = blockIdx.x * 256 + threadIdx.x;
    if (idx >= N_GRAPHS * OUTD) return;
    int g = idx >> 7;
    int o = idx & 127;
    float acc = fcb[o];
#pragma unroll
    for (int k = 0; k < HID; k++) acc = fmaf(pooled[g * HID + k], w[k * OUTD + o], acc);
    out[idx] = fmaxf(acc, 0.f);
}

// ---------------- Launch ----------------

extern "C" void kernel_launch(void* const* d_in, const int* in_sizes, int n_in,
                              void* d_out, int out_size, void* d_ws, size_t ws_size,
                              hipStream_t stream) {
    const float* x = (const float*)d_in[0];
    const int* ei = (const int*)d_in[1];
    const int* batch = (const int*)d_in[2];
    const float* w1_0 = (const float*)d_in[3];
    const float* b1_0 = (const float*)d_in[4];
    const float* w2_0 = (const float*)d_in[5];
    const float* b2_0 = (const float*)d_in[6];
    const float* w1 = (const float*)d_in[7];
    const float* b1 = (const float*)d_in[8];
    const float* w2 = (const float*)d_in[9];
    const float* b2 = (const float*)d_in[10];
    const float* gamma = (const float*)d_in[11];
    const float* beta = (const float*)d_in[12];
    const float* fc_w = (const float*)d_in[13];
    const float* fc_b = (const float*)d_in[14];
    float* out = (float*)d_out;

    const int* e_src = ei;
    const int* e_dst = ei + N_EDGES;

    char* ws = (char*)d_ws;
    size_t off = 0;
    auto alloc = [&](size_t n) {
        void* p = ws + off;
        off += (n + 255) & ~(size_t)255;
        return p;
    };
    int* row_start = (int*)alloc((size_t)NSCAN * 4);
    int* deg = (int*)alloc((size_t)NSCAN * 4);
    int* cursor = (int*)alloc((size_t)N_NODES * 4);
    int* csr = (int*)alloc((size_t)N_EDGES * 4);
    float* agg78 = (float*)alloc((size_t)N_NODES * MOL * 4);
    float* hA = (float*)alloc((size_t)N_NODES * HID * 4);
    float* hB = (float*)alloc((size_t)N_NODES * HID * 4);
    float* bnsums = (float*)alloc(5 * 2 * HID * 4);
    float* scsh = (float*)alloc(5 * 2 * HID * 4);
    float* pooled = (float*)alloc((size_t)N_GRAPHS * HID * 4);
    int* bsum = (int*)alloc(128 * 4);
    int* boff = (int*)alloc(128 * 4);

    hipMemsetAsync(deg, 0, (size_t)NSCAN * 4, stream);
    hipMemsetAsync(bnsums, 0, 5 * 2 * HID * 4, stream);
    hipMemsetAsync(pooled, 0, (size_t)N_GRAPHS * HID * 4, stream);

    // CSR build
    hist_kernel<<<(N_EDGES + 255) / 256, 256, 0, stream>>>(e_dst, deg);
    scan_partial_kernel<<<NBLK, 256, 0, stream>>>(deg, bsum);
    scan_block_kernel<<<1, 64, 0, stream>>>(bsum, boff);
    scan_final_kernel<<<NBLK, 256, 0, stream>>>(deg, boff, row_start);
    cursor_copy_kernel<<<(N_NODES + 255) / 256, 256, 0, stream>>>(row_start, cursor);
    scatter_kernel<<<(N_EDGES + 255) / 256, 256, 0, stream>>>(e_src, e_dst, cursor, csr);

    // Layer 0 (78 -> 32)
    agg78_kernel<<<(N_NODES * 64) / 256, 256, 0, stream>>>(x, row_start, csr, agg78);
    mlp_kernel<MOL><<<(N_NODES + 255) / 256, 256, 0, stream>>>(agg78, w1_0, b1_0, w2_0, b2_0,
                                                               hA, bnsums);
    bnfin_kernel<<<1, 64, 0, stream>>>(bnsums, gamma, beta, scsh);

    // Layers 1..4 (32 -> 32)
    for (int l = 1; l < 5; l++) {
        int i = l - 1;
        agg32_kernel<<<(N_NODES * HID + 255) / 256, 256, 0, stream>>>(
            hA, row_start, csr, scsh + (l - 1) * 2 * HID, hB);
        mlp_kernel<HID><<<(N_NODES + 255) / 256, 256, 0, stream>>>(
            hB, w1 + (size_t)i * HID * HID, b1 + (size_t)i * HID,
            w2 + (size_t)i * HID * HID, b2 + (size_t)i * HID, hA, bnsums + l * 2 * HID);
        bnfin_kernel<<<1, 64, 0, stream>>>(bnsums + l * 2 * HID, gamma + l * HID,
                                           beta + l * HID, scsh + l * 2 * HID);
    }

    // Pool + FC
    pool_kernel<<<(N_NODES * HID + 255) / 256, 256, 0, stream>>>(hA, batch, scsh + 4 * 2 * HID,
                                                                 pooled);
    fc_kernel<<<(N_GRAPHS * OUTD + 255) / 256, 256, 0, stream>>>(pooled, fc_w, fc_b, out);
}

// Round 2
// 999.082 us; speedup vs baseline: 1.6246x; 1.6246x over previous
//
#include <hip/hip_runtime.h>

#define N_NODES 100000
#define N_EDGES 3200000
#define N_GRAPHS 2048
#define MOL 78
#define HID 32
#define OUTD 128
#define BN_EPS 1e-5f

#define NSCAN (N_NODES + 1)
#define SCAN_CHUNK 1024
#define NBLK ((NSCAN + SCAN_CHUNK - 1) / SCAN_CHUNK)  // 98

// ---------------- CSR build ----------------

__global__ void hist_kernel(const int* __restrict__ dst, int* __restrict__ deg) {
    int e = blockIdx.x * blockDim.x + threadIdx.x;
    if (e < N_EDGES) atomicAdd(&deg[dst[e]], 1);
}

__global__ void scan_partial_kernel(const int* __restrict__ deg, int* __restrict__ bsum) {
    int b = blockIdx.x, t = threadIdx.x;
    int base = b * SCAN_CHUNK + t * 4;
    int s = 0;
#pragma unroll
    for (int k = 0; k < 4; k++) {
        int i = base + k;
        if (i < NSCAN) s += deg[i];
    }
    __shared__ int red[256];
    red[t] = s;
    __syncthreads();
    for (int off = 128; off; off >>= 1) {
        if (t < off) red[t] += red[t + off];
        __syncthreads();
    }
    if (t == 0) bsum[b] = red[0];
}

__global__ void scan_block_kernel(const int* __restrict__ bsum, int* __restrict__ boff) {
    if (threadIdx.x == 0 && blockIdx.x == 0) {
        int r = 0;
        for (int b = 0; b < NBLK; b++) {
            boff[b] = r;
            r += bsum[b];
        }
    }
}

__global__ void scan_final_kernel(const int* __restrict__ deg, const int* __restrict__ boff,
                                  int* __restrict__ row_start) {
    int b = blockIdx.x, t = threadIdx.x;
    int base = b * SCAN_CHUNK + t * 4;
    int v[4];
    int tot = 0;
#pragma unroll
    for (int k = 0; k < 4; k++) {
        int i = base + k;
        v[k] = (i < NSCAN) ? deg[i] : 0;
        tot += v[k];
    }
    __shared__ int sc[256];
    sc[t] = tot;
    __syncthreads();
    for (int off = 1; off < 256; off <<= 1) {
        int add = (t >= off) ? sc[t - off] : 0;
        __syncthreads();
        sc[t] += add;
        __syncthreads();
    }
    int run = boff[b] + sc[t] - tot;
#pragma unroll
    for (int k = 0; k < 4; k++) {
        int i = base + k;
        if (i < NSCAN) row_start[i] = run;
        run += v[k];
    }
}

__global__ void cursor_copy_kernel(const int* __restrict__ row_start, int* __restrict__ cursor) {
    int i = blockIdx.x * blockDim.x + threadIdx.x;
    if (i < N_NODES) cursor[i] = row_start[i];
}

__global__ void scatter_kernel(const int* __restrict__ src, const int* __restrict__ dst,
                               int* __restrict__ cursor, int* __restrict__ csr) {
    int e = blockIdx.x * blockDim.x + threadIdx.x;
    if (e < N_EDGES) {
        int d = dst[e];
        int p = atomicAdd(&cursor[d], 1);
        csr[p] = src[e];
    }
}

// ---------------- Projection (x/h -> y = [affine(x)] @ W1) ----------------

template <int KIN, bool AFFINE>
__global__ __launch_bounds__(256) void proj_kernel(const float* __restrict__ in,
                                                   const float* __restrict__ W1,
                                                   const float* __restrict__ scsh,
                                                   float* __restrict__ y) {
    __shared__ float w1s[KIN * HID];
    __shared__ float aff[2 * HID];
    for (int i = threadIdx.x; i < KIN * HID; i += 256) w1s[i] = W1[i];
    if (AFFINE && threadIdx.x < 2 * HID) aff[threadIdx.x] = scsh[threadIdx.x];
    __syncthreads();
    const int node = blockIdx.x * 256 + threadIdx.x;
    if (node >= N_NODES) return;
    const float* row = in + (size_t)node * KIN;
    float acc[HID];
#pragma unroll
    for (int j = 0; j < HID; j++) acc[j] = 0.f;
    const float4* w1v = (const float4*)w1s;
    for (int k = 0; k < KIN; k++) {
        float xv = row[k];
        if (AFFINE) xv = fmaf(xv, aff[k], aff[HID + k]);
#pragma unroll
        for (int q = 0; q < 8; q++) {
            float4 wv = w1v[k * 8 + q];
            acc[4 * q + 0] = fmaf(xv, wv.x, acc[4 * q + 0]);
            acc[4 * q + 1] = fmaf(xv, wv.y, acc[4 * q + 1]);
            acc[4 * q + 2] = fmaf(xv, wv.z, acc[4 * q + 2]);
            acc[4 * q + 3] = fmaf(xv, wv.w, acc[4 * q + 3]);
        }
    }
    float4* o = (float4*)(y + (size_t)node * HID);
#pragma unroll
    for (int q = 0; q < 8; q++)
        o[q] = make_float4(acc[4 * q], acc[4 * q + 1], acc[4 * q + 2], acc[4 * q + 3]);
}

// ---------------- Aggregation: pure 32-dim sum over CSR ----------------
// Half-wave (32 lanes) per node: 4 edge slots x 8 lanes, each lane reads float4
// (8 lanes x 16B = one coalesced 128B row). Unroll x2 -> 8 rows in flight.

__global__ __launch_bounds__(256) void agg_kernel(const float* __restrict__ y,
                                                  const int* __restrict__ rs,
                                                  const int* __restrict__ csr,
                                                  float* __restrict__ agg) {
    int gt = blockIdx.x * blockDim.x + threadIdx.x;
    int node = gt >> 5;
    if (node >= N_NODES) return;
    int hl = threadIdx.x & 31;  // lane within half-wave
    int s = hl >> 3;            // edge slot 0..3
    int q = hl & 7;             // float4 quad (channels 4q..4q+3)
    const float4* rows = (const float4*)y;
    float4 acc = (s == 0) ? rows[(size_t)node * 8 + q] : make_float4(0.f, 0.f, 0.f, 0.f);
    int e0 = rs[node], e1 = rs[node + 1];
    int k = e0 + s;
    for (; k + 4 < e1; k += 8) {
        int j0 = csr[k];
        int j1 = csr[k + 4];
        float4 v0 = rows[(size_t)j0 * 8 + q];
        float4 v1 = rows[(size_t)j1 * 8 + q];
        acc.x += v0.x + v1.x;
        acc.y += v0.y + v1.y;
        acc.z += v0.z + v1.z;
        acc.w += v0.w + v1.w;
    }
    if (k < e1) {
        int j = csr[k];
        float4 v = rows[(size_t)j * 8 + q];
        acc.x += v.x;
        acc.y += v.y;
        acc.z += v.z;
        acc.w += v.w;
    }
    // combine the 4 edge slots: xor 8, xor 16 within the 32-lane half-wave
#pragma unroll
    for (int m = 8; m <= 16; m <<= 1) {
        acc.x += __shfl_xor(acc.x, m, 32);
        acc.y += __shfl_xor(acc.y, m, 32);
        acc.z += __shfl_xor(acc.z, m, 32);
        acc.w += __shfl_xor(acc.w, m, 32);
    }
    if (s == 0) ((float4*)agg)[(size_t)node * 8 + q] = acc;
}

// ---------------- Second half of MLP + BN stats ----------------
// h = ReLU(ReLU(agg + B1) @ W2 + B2); accumulate per-column sum/sumsq.

__global__ __launch_bounds__(256) void mlp2_kernel(const float* __restrict__ agg,
                                                   const float* __restrict__ B1,
                                                   const float* __restrict__ W2,
                                                   const float* __restrict__ B2,
                                                   float* __restrict__ out,
                                                   float* __restrict__ sums) {
    __shared__ float w2s[HID * HID];
    __shared__ float bs[2 * HID];
    __shared__ float ssum[2 * HID];
    for (int i = threadIdx.x; i < HID * HID; i += 256) w2s[i] = W2[i];
    if (threadIdx.x < HID) {
        bs[threadIdx.x] = B1[threadIdx.x];
        bs[HID + threadIdx.x] = B2[threadIdx.x];
    }
    if (threadIdx.x < 2 * HID) ssum[threadIdx.x] = 0.f;
    __syncthreads();

    const int node = blockIdx.x * 256 + threadIdx.x;
    const bool active = node < N_NODES;

    float v[HID];
#pragma unroll
    for (int j = 0; j < HID; j++) v[j] = 0.f;
    if (active) {
        const float4* a = (const float4*)(agg + (size_t)node * HID);
#pragma unroll
        for (int q = 0; q < 8; q++) {
            float4 t = a[q];
            v[4 * q + 0] = t.x;
            v[4 * q + 1] = t.y;
            v[4 * q + 2] = t.z;
            v[4 * q + 3] = t.w;
        }
    }
#pragma unroll
    for (int j = 0; j < HID; j++) v[j] = fmaxf(v[j] + bs[j], 0.f);

    float h2[HID];
#pragma unroll
    for (int j = 0; j < HID; j++) h2[j] = bs[HID + j];
    const float4* w2v = (const float4*)w2s;
#pragma unroll
    for (int k = 0; k < HID; k++) {
        float z = v[k];
#pragma unroll
        for (int q = 0; q < 8; q++) {
            float4 wv = w2v[k * 8 + q];
            h2[4 * q + 0] = fmaf(z, wv.x, h2[4 * q + 0]);
            h2[4 * q + 1] = fmaf(z, wv.y, h2[4 * q + 1]);
            h2[4 * q + 2] = fmaf(z, wv.z, h2[4 * q + 2]);
            h2[4 * q + 3] = fmaf(z, wv.w, h2[4 * q + 3]);
        }
    }
#pragma unroll
    for (int j = 0; j < HID; j++) h2[j] = fmaxf(h2[j], 0.f);

    if (active) {
        float4* o = (float4*)(out + (size_t)node * HID);
#pragma unroll
        for (int q = 0; q < 8; q++)
            o[q] = make_float4(h2[4 * q], h2[4 * q + 1], h2[4 * q + 2], h2[4 * q + 3]);
    }

    int lane = threadIdx.x & 63;
#pragma unroll
    for (int j = 0; j < HID; j++) {
        float a = active ? h2[j] : 0.f;
        float a2 = a * a;
#pragma unroll
        for (int off = 32; off; off >>= 1) {
            a += __shfl_down(a, off, 64);
            a2 += __shfl_down(a2, off, 64);
        }
        if (lane == 0) {
            atomicAdd(&ssum[j], a);
            atomicAdd(&ssum[HID + j], a2);
        }
    }
    __syncthreads();
    if (threadIdx.x < 2 * HID) atomicAdd(&sums[threadIdx.x], ssum[threadIdx.x]);
}

__global__ void bnfin_kernel(const float* __restrict__ sums, const float* __restrict__ g,
                             const float* __restrict__ bt, float* __restrict__ scsh) {
    int j = threadIdx.x;
    if (j < HID) {
        float m = sums[j] * (1.0f / N_NODES);
        float var = sums[HID + j] * (1.0f / N_NODES) - m * m;
        var = fmaxf(var, 0.f);
        float sc = g[j] * rsqrtf(var + BN_EPS);
        scsh[j] = sc;
        scsh[HID + j] = bt[j] - m * sc;
    }
}

// ---------------- Pooling + FC ----------------

__global__ void pool_kernel(const float* __restrict__ h, const int* __restrict__ batch,
                            const float* __restrict__ scsh, float* __restrict__ pooled) {
    int gt = blockIdx.x * blockDim.x + threadIdx.x;
    if (gt >= N_NODES * HID) return;
    int node = gt >> 5;
    int c = gt & 31;
    int g = batch[node];
    float v = fmaf(h[gt], scsh[c], scsh[HID + c]);
    atomicAdd(&pooled[g * HID + c], v);
}

__global__ void fc_kernel(const float* __restrict__ pooled, const float* __restrict__ fcw,
                          const float* __restrict__ fcb, float* __restrict__ out) {
    __shared__ float w[HID * OUTD];
    for (int i = threadIdx.x; i < HID * OUTD; i += 256) w[i] = fcw[i];
    __syncthreads();
    int idx = blockIdx.x * 256 + threadIdx.x;
    if (idx >= N_GRAPHS * OUTD) return;
    int g = idx >> 7;
    int o = idx & 127;
    float acc = fcb[o];
#pragma unroll
    for (int k = 0; k < HID; k++) acc = fmaf(pooled[g * HID + k], w[k * OUTD + o], acc);
    out[idx] = fmaxf(acc, 0.f);
}

// ---------------- Launch ----------------

extern "C" void kernel_launch(void* const* d_in, const int* in_sizes, int n_in,
                              void* d_out, int out_size, void* d_ws, size_t ws_size,
                              hipStream_t stream) {
    const float* x = (const float*)d_in[0];
    const int* ei = (const int*)d_in[1];
    const int* batch = (const int*)d_in[2];
    const float* w1_0 = (const float*)d_in[3];
    const float* b1_0 = (const float*)d_in[4];
    const float* w2_0 = (const float*)d_in[5];
    const float* b2_0 = (const float*)d_in[6];
    const float* w1 = (const float*)d_in[7];
    const float* b1 = (const float*)d_in[8];
    const float* w2 = (const float*)d_in[9];
    const float* b2 = (const float*)d_in[10];
    const float* gamma = (const float*)d_in[11];
    const float* beta = (const float*)d_in[12];
    const float* fc_w = (const float*)d_in[13];
    const float* fc_b = (const float*)d_in[14];
    float* out = (float*)d_out;

    const int* e_src = ei;
    const int* e_dst = ei + N_EDGES;

    char* ws = (char*)d_ws;
    size_t off = 0;
    auto alloc = [&](size_t n) {
        void* p = ws + off;
        off += (n + 255) & ~(size_t)255;
        return p;
    };
    int* row_start = (int*)alloc((size_t)NSCAN * 4);
    int* deg = (int*)alloc((size_t)NSCAN * 4);
    int* cursor = (int*)alloc((size_t)N_NODES * 4);
    int* csr = (int*)alloc((size_t)N_EDGES * 4);
    float* ybuf = (float*)alloc((size_t)N_NODES * HID * 4);
    float* aggb = (float*)alloc((size_t)N_NODES * HID * 4);
    float* hbuf = (float*)alloc((size_t)N_NODES * HID * 4);
    float* bnsums = (float*)alloc(5 * 2 * HID * 4);
    float* scsh = (float*)alloc(5 * 2 * HID * 4);
    float* pooled = (float*)alloc((size_t)N_GRAPHS * HID * 4);
    int* bsum = (int*)alloc(128 * 4);
    int* boff = (int*)alloc(128 * 4);

    hipMemsetAsync(deg, 0, (size_t)NSCAN * 4, stream);
    hipMemsetAsync(bnsums, 0, 5 * 2 * HID * 4, stream);
    hipMemsetAsync(pooled, 0, (size_t)N_GRAPHS * HID * 4, stream);

    // CSR build
    hist_kernel<<<(N_EDGES + 255) / 256, 256, 0, stream>>>(e_dst, deg);
    scan_partial_kernel<<<NBLK, 256, 0, stream>>>(deg, bsum);
    scan_block_kernel<<<1, 64, 0, stream>>>(bsum, boff);
    scan_final_kernel<<<NBLK, 256, 0, stream>>>(deg, boff, row_start);
    cursor_copy_kernel<<<(N_NODES + 255) / 256, 256, 0, stream>>>(row_start, cursor);
    scatter_kernel<<<(N_EDGES + 255) / 256, 256, 0, stream>>>(e_src, e_dst, cursor, csr);

    const int nodeBlocks = (N_NODES + 255) / 256;
    const int aggBlocks = (N_NODES * 32 + 255) / 256;

    // Layer 0: project first (agg is linear, commutes with W1), then aggregate in 32-dim
    proj_kernel<MOL, false><<<nodeBlocks, 256, 0, stream>>>(x, w1_0, nullptr, ybuf);
    agg_kernel<<<aggBlocks, 256, 0, stream>>>(ybuf, row_start, csr, aggb);
    mlp2_kernel<<<nodeBlocks, 256, 0, stream>>>(aggb, b1_0, w2_0, b2_0, hbuf, bnsums);
    bnfin_kernel<<<1, 64, 0, stream>>>(bnsums, gamma, beta, scsh);

    // Layers 1..4: fold BN affine into projection, aggregate pure sums
    for (int l = 1; l < 5; l++) {
        int i = l - 1;
        proj_kernel<HID, true><<<nodeBlocks, 256, 0, stream>>>(
            hbuf, w1 + (size_t)i * HID * HID, scsh + (l - 1) * 2 * HID, ybuf);
        agg_kernel<<<aggBlocks, 256, 0, stream>>>(ybuf, row_start, csr, aggb);
        mlp2_kernel<<<nodeBlocks, 256, 0, stream>>>(
            aggb, b1 + (size_t)i * HID, w2 + (size_t)i * HID * HID, b2 + (size_t)i * HID,
            hbuf, bnsums + l * 2 * HID);
        bnfin_kernel<<<1, 64, 0, stream>>>(bnsums + l * 2 * HID, gamma + l * HID,
                                           beta + l * HID, scsh + l * 2 * HID);
    }

    // Pool + FC
    pool_kernel<<<(N_NODES * HID + 255) / 256, 256, 0, stream>>>(hbuf, batch, scsh + 4 * 2 * HID,
                                                                 pooled);
    fc_kernel<<<(N_GRAPHS * OUTD + 255) / 256, 256, 0, stream>>>(pooled, fc_w, fc_b, out);
}